// Round 1
// baseline (7500.197 us; speedup 1.0000x reference)
//
#include <hip/hip_runtime.h>

// ---------- types / helpers ----------
typedef unsigned short u16;
typedef short  s16x8 __attribute__((ext_vector_type(8)));
typedef float  f32x4 __attribute__((ext_vector_type(4)));
typedef unsigned short u16x4 __attribute__((ext_vector_type(4)));

#define LDS_AS __attribute__((address_space(3)))
#define GLB_AS __attribute__((address_space(1)))

__device__ __forceinline__ float bf2f(u16 x) {
    unsigned u = ((unsigned)x) << 16;
    return __builtin_bit_cast(float, u);
}
__device__ __forceinline__ u16 f2bf(float f) {
    unsigned u = __builtin_bit_cast(unsigned, f);
    return (u16)((u + 0x7FFFu + ((u >> 16) & 1u)) >> 16);  // RNE
}
__device__ __forceinline__ void gload16(const u16* g, u16* l) {
    __builtin_amdgcn_global_load_lds((const GLB_AS unsigned int*)g,
                                     (LDS_AS unsigned int*)l, 16, 0, 0);
}

static constexpr int Lc = 4, Sc = 2048, Dc = 1024, Hc = 2048, Mc = 8192;

// ---------- GEMM: C[M,N] = A[M,K] @ Bw[N,K]^T + bias ----------
// CONV=1: logical K=3*H, A is s1[M,H] (lda=H); k-segment seg=k0>>11 shifts the
//         A row by seg-1 (zero pad at batch edges via zerobuf redirect).
// EPI=0: store bf16 to Cb. EPI=1: v += resid (fp32); store fp32 to Cf and bf16 to xout.
template <int CONV, int EPI>
__global__ __launch_bounds__(256)
void gemm_bt(const u16* __restrict__ A, const u16* __restrict__ Bw,
             const float* __restrict__ bias,
             u16* __restrict__ Cb, float* __restrict__ Cf,
             const float* __restrict__ resid, u16* __restrict__ xout,
             int M, int N, int K, int lda, const u16* __restrict__ zerobuf) {
    __shared__ __align__(16) u16 As[128 * 32];
    __shared__ __align__(16) u16 Bs[128 * 32];
    const int tid  = threadIdx.x;
    const int wave = tid >> 6, lane = tid & 63;
    const int rowBase = blockIdx.y * 128;
    const int colBase = blockIdx.x * 128;
    const int srow = tid >> 2;          // staging row within 0..63
    const int scol = (tid & 3) << 3;    // staging col (elements)

    u16* ldsA0 = As + wave * 512;
    u16* ldsA1 = As + 2048 + wave * 512;
    u16* ldsB0 = Bs + wave * 512;
    u16* ldsB1 = Bs + 2048 + wave * 512;

    const u16* bpt0 = Bw + (size_t)(colBase + srow) * K + scol;
    const u16* bpt1 = Bw + (size_t)(colBase + 64 + srow) * K + scol;
    const int arow0 = rowBase + srow;
    const int arow1 = arow0 + 64;
    const u16* ap0 = A + (size_t)arow0 * lda + scol;
    const u16* ap1 = A + (size_t)arow1 * lda + scol;

    const int wm = wave & 1, wn = wave >> 1;
    const int mB = wm * 64, nB = wn * 64;
    const int quad = lane >> 4, l16 = lane & 15;

    f32x4 acc[4][4];
#pragma unroll
    for (int a = 0; a < 4; a++)
#pragma unroll
        for (int b = 0; b < 4; b++)
#pragma unroll
            for (int r = 0; r < 4; r++) acc[a][b][r] = 0.f;

    for (int k0 = 0; k0 < K; k0 += 32) {
        if (CONV) {
            const int seg = k0 >> 11;                 // /H
            const int kk  = (k0 & (Hc - 1)) + scol;
            const int bb  = rowBase & ~(Sc - 1);      // batch start (flat row)
            const int r0  = arow0 + seg - 1;
            const int r1  = arow1 + seg - 1;
            const u16* g0 = ((unsigned)(r0 - bb) < (unsigned)Sc) ? A + (size_t)r0 * lda + kk : zerobuf;
            const u16* g1 = ((unsigned)(r1 - bb) < (unsigned)Sc) ? A + (size_t)r1 * lda + kk : zerobuf;
            gload16(g0, ldsA0);
            gload16(g1, ldsA1);
        } else {
            gload16(ap0 + k0, ldsA0);
            gload16(ap1 + k0, ldsA1);
        }
        gload16(bpt0 + k0, ldsB0);
        gload16(bpt1 + k0, ldsB1);
        __syncthreads();

        s16x8 af[4], bfr[4];
#pragma unroll
        for (int t = 0; t < 4; t++)
            af[t] = *(const s16x8*)(As + (mB + t * 16 + l16) * 32 + (quad << 3));
#pragma unroll
        for (int t = 0; t < 4; t++)
            bfr[t] = *(const s16x8*)(Bs + (nB + t * 16 + l16) * 32 + (quad << 3));
#pragma unroll
        for (int mt = 0; mt < 4; mt++)
#pragma unroll
            for (int nt = 0; nt < 4; nt++)
                acc[mt][nt] = __builtin_amdgcn_mfma_f32_16x16x32_bf16(af[mt], bfr[nt], acc[mt][nt], 0, 0, 0);
        __syncthreads();
    }

#pragma unroll
    for (int mt = 0; mt < 4; mt++) {
#pragma unroll
        for (int nt = 0; nt < 4; nt++) {
            const int col  = colBase + nB + nt * 16 + l16;
            const int row0 = rowBase + mB + mt * 16 + (quad << 2);
            const float bv = bias[col];
#pragma unroll
            for (int r = 0; r < 4; r++) {
                const size_t idx = (size_t)(row0 + r) * N + col;
                float v = acc[mt][nt][r] + bv;
                if (EPI == 0) {
                    Cb[idx] = f2bf(v);
                } else {
                    v += resid[idx];
                    Cf[idx]   = v;
                    xout[idx] = f2bf(v);
                }
            }
        }
    }
}

// ---------- LayerNorm over H=2048 (+ optional SiLU, + optional elementwise mul) ----------
__global__ __launch_bounds__(256)
void ln_fuse(const u16* __restrict__ in, u16* __restrict__ out,
             const float* __restrict__ g, const float* __restrict__ b,
             const u16* __restrict__ mul, int do_silu) {
    __shared__ float sred[4], qred[4];
    const int row = blockIdx.x, tid = threadIdx.x;
    const int lane = tid & 63, wave = tid >> 6;
    const size_t base = (size_t)row * Hc + tid * 8;

    s16x8 v8 = *(const s16x8*)(in + base);
    float x[8];
#pragma unroll
    for (int j = 0; j < 8; j++) x[j] = bf2f((u16)v8[j]);
    float s = 0.f, q = 0.f;
#pragma unroll
    for (int j = 0; j < 8; j++) { s += x[j]; q += x[j] * x[j]; }
#pragma unroll
    for (int off = 32; off > 0; off >>= 1) {
        s += __shfl_down(s, off);
        q += __shfl_down(q, off);
    }
    if (lane == 0) { sred[wave] = s; qred[wave] = q; }
    __syncthreads();
    const float St = sred[0] + sred[1] + sred[2] + sred[3];
    const float Qt = qred[0] + qred[1] + qred[2] + qred[3];
    const float mean = St * (1.0f / Hc);
    const float var  = Qt * (1.0f / Hc) - mean * mean;
    const float rs   = rsqrtf(var + 1e-5f);

    const int c = tid * 8;
    const float4 g0 = *(const float4*)(g + c), g1 = *(const float4*)(g + c + 4);
    const float4 b0 = *(const float4*)(b + c), b1 = *(const float4*)(b + c + 4);
    const float gg[8] = {g0.x, g0.y, g0.z, g0.w, g1.x, g1.y, g1.z, g1.w};
    const float bb[8] = {b0.x, b0.y, b0.z, b0.w, b1.x, b1.y, b1.z, b1.w};
    s16x8 m8;
    if (mul) m8 = *(const s16x8*)(mul + base);
    s16x8 o8;
#pragma unroll
    for (int j = 0; j < 8; j++) {
        float y = (x[j] - mean) * rs * gg[j] + bb[j];
        if (do_silu) y = y / (1.0f + __expf(-y));
        if (mul) y *= bf2f((u16)m8[j]);
        o8[j] = (short)f2bf(y);
    }
    *(s16x8*)(out + base) = o8;
}

// ---------- minGRU log-space sequential scan (one thread per (b,h) channel) ----------
__global__ __launch_bounds__(256)
void gru_scan(const u16* __restrict__ kb, const u16* __restrict__ pb, u16* __restrict__ out) {
    const int id = blockIdx.x * 256 + threadIdx.x;   // 0..8191 = b*H + h
    const int bb = id >> 11, h = id & (Hc - 1);
    size_t idx = (size_t)bb * ((size_t)Sc * Hc) + h;
    float lh = -0.69314718f;  // log 0.5 = log_g(0)
    for (int t = 0; t < Sc; t++) {
        const float k = bf2f(kb[idx]);
        const float p = bf2f(pb[idx]);
        const float l1p = __logf(1.f + __expf(-fabsf(k)));
        const float sp_pos = fmaxf(k, 0.f) + l1p;    // softplus(k)
        const float sp_neg = fmaxf(-k, 0.f) + l1p;   // softplus(-k)
        const float c = -sp_pos;                      // log_coeffs
        const float lg = (p >= 0.f) ? __logf(p + 0.5f)
                                    : -(fmaxf(-p, 0.f) + __logf(1.f + __expf(-fabsf(p))));
        const float v = -sp_neg + lg;                 // log_z + log_tilde_h
        const float a = lh + c;
        const float m = fmaxf(a, v);
        lh = m + __logf(1.f + __expf(-fabsf(a - v)));
        out[idx] = f2bf(__expf(lh));
        idx += Hc;
    }
}

// ---------- casts ----------
__global__ __launch_bounds__(256)
void castf2b(const float* __restrict__ in, u16* __restrict__ out, int n) {
    const int i = (blockIdx.x * 256 + threadIdx.x) << 2;
    if (i >= n) return;
    const float4 v = *(const float4*)(in + i);
    u16x4 o;
    o.x = f2bf(v.x); o.y = f2bf(v.y); o.z = f2bf(v.z); o.w = f2bf(v.w);
    *(u16x4*)(out + i) = o;
}

// convW (H,H,3) -> wt (H, 3H): wt[o][k*H + i] = w[o][i][k]  (bf16)
__global__ __launch_bounds__(256)
void conv_tr(const float* __restrict__ w, u16* __restrict__ out) {
    const int idx = blockIdx.x * 256 + threadIdx.x;  // o*H + i
    const float* src = w + (size_t)idx * 3;
    const float a = src[0], b = src[1], c = src[2];
    const int o = idx >> 11, ii = idx & (Hc - 1);
    u16* dst = out + (size_t)o * (3 * Hc) + ii;
    dst[0]        = f2bf(a);
    dst[Hc]       = f2bf(b);
    dst[2 * Hc]   = f2bf(c);
}

// ---------- host ----------
static inline void launch_gemm(int conv, int epi,
                               const u16* A, const u16* Bw, const float* bias,
                               u16* Cb, float* Cf, const float* resid, u16* xout,
                               int M, int N, int K, int lda, const u16* zero, hipStream_t s) {
    dim3 grid(N / 128, M / 128), blk(256);
    if (conv)
        gemm_bt<1, 0><<<grid, blk, 0, s>>>(A, Bw, bias, Cb, Cf, resid, xout, M, N, K, lda, zero);
    else if (epi)
        gemm_bt<0, 1><<<grid, blk, 0, s>>>(A, Bw, bias, Cb, Cf, resid, xout, M, N, K, lda, zero);
    else
        gemm_bt<0, 0><<<grid, blk, 0, s>>>(A, Bw, bias, Cb, Cf, resid, xout, M, N, K, lda, zero);
}

extern "C" void kernel_launch(void* const* d_in, const int* in_sizes, int n_in,
                              void* d_out, int out_size, void* d_ws, size_t ws_size,
                              hipStream_t stream) {
    (void)in_sizes; (void)n_in; (void)out_size; (void)ws_size;
    const float* x0    = (const float*)d_in[0];
    const float* Wp1   = (const float*)d_in[1];
    const float* bp1   = (const float*)d_in[2];
    const float* Wp2   = (const float*)d_in[3];
    const float* bp2   = (const float*)d_in[4];
    const float* convW = (const float*)d_in[5];
    const float* convb = (const float*)d_in[6];
    const float* Wz    = (const float*)d_in[7];
    const float* bz    = (const float*)d_in[8];
    const float* Wh    = (const float*)d_in[9];
    const float* bh    = (const float*)d_in[10];
    const float* Wd    = (const float*)d_in[11];
    const float* bd    = (const float*)d_in[12];
    const float* lng   = (const float*)d_in[13];
    const float* lnb   = (const float*)d_in[14];
    float* out = (float*)d_out;

    // ws layout (bytes)
    char* ws = (char*)d_ws;
    u16* wbuf = (u16*)(ws);                       // 12,582,912 elems (max weight: conv)
    u16* s1   = (u16*)(ws + 25165824);            // 16,777,216 elems each below
    u16* t1   = (u16*)(ws + 58720256);
    u16* s2   = (u16*)(ws + 92274688);            // doubles as kb
    u16* pbuf = (u16*)(ws + 125829120);
    u16* xb   = (u16*)(ws + 159383552);           // 8,388,608 elems
    u16* zero = (u16*)(ws + 176160768);           // 1 KiB zero page

    hipMemsetAsync(zero, 0, 1024, stream);
    castf2b<<<dim3((Mc * Dc / 4) / 256), dim3(256), 0, stream>>>(x0, xb, Mc * Dc);

    const size_t wpStride = (size_t)Hc * Dc;      // 2,097,152
    const size_t cvStride = (size_t)Hc * Hc * 3;  // 12,582,912
    const size_t wzStride = (size_t)Hc * Hc;      // 4,194,304
    const size_t wdStride = (size_t)Dc * Hc;      // 2,097,152

    for (int i = 0; i < Lc; ++i) {
        const float* g0 = lng + ((size_t)i * 4 + 0) * Hc; const float* be0 = lnb + ((size_t)i * 4 + 0) * Hc;
        const float* g1 = lng + ((size_t)i * 4 + 1) * Hc; const float* be1 = lnb + ((size_t)i * 4 + 1) * Hc;
        const float* g2 = lng + ((size_t)i * 4 + 2) * Hc; const float* be2 = lnb + ((size_t)i * 4 + 2) * Hc;
        const float* g3 = lng + ((size_t)i * 4 + 3) * Hc; const float* be3 = lnb + ((size_t)i * 4 + 3) * Hc;

        // strand 1: proj1 + LN0
        castf2b<<<dim3((int)(wpStride / 4 / 256)), dim3(256), 0, stream>>>(Wp1 + i * wpStride, wbuf, (int)wpStride);
        launch_gemm(0, 0, xb, wbuf, bp1 + (size_t)i * Hc, t1, nullptr, nullptr, nullptr,
                    Mc, Hc, Dc, Dc, zero, stream);
        ln_fuse<<<dim3(Mc), dim3(256), 0, stream>>>(t1, s1, g0, be0, nullptr, 0);

        // conv1d (as GEMM over K=3H) + LN1 + SiLU
        conv_tr<<<dim3((Hc * Hc) / 256), dim3(256), 0, stream>>>(convW + i * cvStride, wbuf);
        launch_gemm(1, 0, s1, wbuf, convb + (size_t)i * Hc, t1, nullptr, nullptr, nullptr,
                    Mc, Hc, 3 * Hc, Hc, zero, stream);
        ln_fuse<<<dim3(Mc), dim3(256), 0, stream>>>(t1, s1, g1, be1, nullptr, 1);

        // minGRU: k = s1@Wz^T+bz ; p = s1@Wh^T+bh ; scan ; LN2
        castf2b<<<dim3((int)(wzStride / 4 / 256)), dim3(256), 0, stream>>>(Wz + i * wzStride, wbuf, (int)wzStride);
        launch_gemm(0, 0, s1, wbuf, bz + (size_t)i * Hc, s2, nullptr, nullptr, nullptr,
                    Mc, Hc, Hc, Hc, zero, stream);
        castf2b<<<dim3((int)(wzStride / 4 / 256)), dim3(256), 0, stream>>>(Wh + i * wzStride, wbuf, (int)wzStride);
        launch_gemm(0, 0, s1, wbuf, bh + (size_t)i * Hc, pbuf, nullptr, nullptr, nullptr,
                    Mc, Hc, Hc, Hc, zero, stream);
        gru_scan<<<dim3(32), dim3(256), 0, stream>>>(s2, pbuf, t1);
        ln_fuse<<<dim3(Mc), dim3(256), 0, stream>>>(t1, s1, g2, be2, nullptr, 0);

        // strand 2: proj2 + LN3 + SiLU, fused multiply by s1 -> s2
        castf2b<<<dim3((int)(wpStride / 4 / 256)), dim3(256), 0, stream>>>(Wp2 + i * wpStride, wbuf, (int)wpStride);
        launch_gemm(0, 0, xb, wbuf, bp2 + (size_t)i * Hc, t1, nullptr, nullptr, nullptr,
                    Mc, Hc, Dc, Dc, zero, stream);
        ln_fuse<<<dim3(Mc), dim3(256), 0, stream>>>(t1, s2, g3, be3, s1, 1);

        // down proj + bias + residual; write fp32 x to d_out and bf16 x to xb
        castf2b<<<dim3((int)(wdStride / 4 / 256)), dim3(256), 0, stream>>>(Wd + i * wdStride, wbuf, (int)wdStride);
        launch_gemm(0, 1, s2, wbuf, bd + (size_t)i * Dc, nullptr, out,
                    (i == 0) ? x0 : out, xb, Mc, Dc, Hc, Hc, zero, stream);
    }
}

// Round 2
// 3972.852 us; speedup vs baseline: 1.8879x; 1.8879x over previous
//
#include <hip/hip_runtime.h>

// ---------- types / helpers ----------
typedef unsigned short u16;
typedef short  s16x8 __attribute__((ext_vector_type(8)));
typedef float  f32x4 __attribute__((ext_vector_type(4)));
typedef unsigned short u16x4 __attribute__((ext_vector_type(4)));

#define LDS_AS __attribute__((address_space(3)))
#define GLB_AS __attribute__((address_space(1)))

__device__ __forceinline__ float bf2f(u16 x) {
    unsigned u = ((unsigned)x) << 16;
    return __builtin_bit_cast(float, u);
}
__device__ __forceinline__ u16 f2bf(float f) {
    unsigned u = __builtin_bit_cast(unsigned, f);
    return (u16)((u + 0x7FFFu + ((u >> 16) & 1u)) >> 16);  // RNE
}
__device__ __forceinline__ void gload16(const u16* g, u16* l) {
    __builtin_amdgcn_global_load_lds((const GLB_AS unsigned int*)g,
                                     (LDS_AS unsigned int*)l, 16, 0, 0);
}

static constexpr int Lc = 4, Sc = 2048, Dc = 1024, Hc = 2048, Mc = 8192;
static constexpr int CH = 64, CL = 32;  // scan chunks / chunk length (CH*CL == Sc)
static constexpr int NCHAN = 4 * Hc;    // B*H = 8192 channels

// ---------- GEMM: C[M,N] = A[M,K] @ Bw[N,K]^T + bias ----------
// CONV=1: logical K=3*H, A is s1[M,H] (lda=H); k-segment seg=k0>>11 shifts the
//         A row by seg-1 (zero pad at batch edges via zerobuf redirect).
// EPI=0: store bf16 to Cb. EPI=1: v += resid (fp32); store fp32 to Cf and bf16 to xout.
template <int CONV, int EPI>
__global__ __launch_bounds__(256)
void gemm_bt(const u16* __restrict__ A, const u16* __restrict__ Bw,
             const float* __restrict__ bias,
             u16* __restrict__ Cb, float* __restrict__ Cf,
             const float* __restrict__ resid, u16* __restrict__ xout,
             int M, int N, int K, int lda, const u16* __restrict__ zerobuf) {
    __shared__ __align__(16) u16 As[128 * 32];
    __shared__ __align__(16) u16 Bs[128 * 32];
    const int tid  = threadIdx.x;
    const int wave = tid >> 6, lane = tid & 63;
    const int rowBase = blockIdx.y * 128;
    const int colBase = blockIdx.x * 128;
    const int srow = tid >> 2;          // staging row within 0..63
    const int scol = (tid & 3) << 3;    // staging col (elements)

    u16* ldsA0 = As + wave * 512;
    u16* ldsA1 = As + 2048 + wave * 512;
    u16* ldsB0 = Bs + wave * 512;
    u16* ldsB1 = Bs + 2048 + wave * 512;

    const u16* bpt0 = Bw + (size_t)(colBase + srow) * K + scol;
    const u16* bpt1 = Bw + (size_t)(colBase + 64 + srow) * K + scol;
    const int arow0 = rowBase + srow;
    const int arow1 = arow0 + 64;
    const u16* ap0 = A + (size_t)arow0 * lda + scol;
    const u16* ap1 = A + (size_t)arow1 * lda + scol;

    const int wm = wave & 1, wn = wave >> 1;
    const int mB = wm * 64, nB = wn * 64;
    const int quad = lane >> 4, l16 = lane & 15;

    f32x4 acc[4][4];
#pragma unroll
    for (int a = 0; a < 4; a++)
#pragma unroll
        for (int b = 0; b < 4; b++)
#pragma unroll
            for (int r = 0; r < 4; r++) acc[a][b][r] = 0.f;

    for (int k0 = 0; k0 < K; k0 += 32) {
        if (CONV) {
            const int seg = k0 >> 11;                 // /H
            const int kk  = (k0 & (Hc - 1)) + scol;
            const int bb  = rowBase & ~(Sc - 1);      // batch start (flat row)
            const int r0  = arow0 + seg - 1;
            const int r1  = arow1 + seg - 1;
            const u16* g0 = ((unsigned)(r0 - bb) < (unsigned)Sc) ? A + (size_t)r0 * lda + kk : zerobuf;
            const u16* g1 = ((unsigned)(r1 - bb) < (unsigned)Sc) ? A + (size_t)r1 * lda + kk : zerobuf;
            gload16(g0, ldsA0);
            gload16(g1, ldsA1);
        } else {
            gload16(ap0 + k0, ldsA0);
            gload16(ap1 + k0, ldsA1);
        }
        gload16(bpt0 + k0, ldsB0);
        gload16(bpt1 + k0, ldsB1);
        __syncthreads();

        s16x8 af[4], bfr[4];
#pragma unroll
        for (int t = 0; t < 4; t++)
            af[t] = *(const s16x8*)(As + (mB + t * 16 + l16) * 32 + (quad << 3));
#pragma unroll
        for (int t = 0; t < 4; t++)
            bfr[t] = *(const s16x8*)(Bs + (nB + t * 16 + l16) * 32 + (quad << 3));
#pragma unroll
        for (int mt = 0; mt < 4; mt++)
#pragma unroll
            for (int nt = 0; nt < 4; nt++)
                acc[mt][nt] = __builtin_amdgcn_mfma_f32_16x16x32_bf16(af[mt], bfr[nt], acc[mt][nt], 0, 0, 0);
        __syncthreads();
    }

#pragma unroll
    for (int mt = 0; mt < 4; mt++) {
#pragma unroll
        for (int nt = 0; nt < 4; nt++) {
            const int col  = colBase + nB + nt * 16 + l16;
            const int row0 = rowBase + mB + mt * 16 + (quad << 2);
            const float bv = bias[col];
#pragma unroll
            for (int r = 0; r < 4; r++) {
                const size_t idx = (size_t)(row0 + r) * N + col;
                float v = acc[mt][nt][r] + bv;
                if (EPI == 0) {
                    Cb[idx] = f2bf(v);
                } else {
                    v += resid[idx];
                    Cf[idx]   = v;
                    xout[idx] = f2bf(v);
                }
            }
        }
    }
}

// ---------- LayerNorm over H=2048 (+ optional SiLU, + optional elementwise mul) ----------
__global__ __launch_bounds__(256)
void ln_fuse(const u16* __restrict__ in, u16* __restrict__ out,
             const float* __restrict__ g, const float* __restrict__ b,
             const u16* __restrict__ mul, int do_silu) {
    __shared__ float sred[4], qred[4];
    const int row = blockIdx.x, tid = threadIdx.x;
    const int lane = tid & 63, wave = tid >> 6;
    const size_t base = (size_t)row * Hc + tid * 8;

    s16x8 v8 = *(const s16x8*)(in + base);
    float x[8];
#pragma unroll
    for (int j = 0; j < 8; j++) x[j] = bf2f((u16)v8[j]);
    float s = 0.f, q = 0.f;
#pragma unroll
    for (int j = 0; j < 8; j++) { s += x[j]; q += x[j] * x[j]; }
#pragma unroll
    for (int off = 32; off > 0; off >>= 1) {
        s += __shfl_down(s, off);
        q += __shfl_down(q, off);
    }
    if (lane == 0) { sred[wave] = s; qred[wave] = q; }
    __syncthreads();
    const float St = sred[0] + sred[1] + sred[2] + sred[3];
    const float Qt = qred[0] + qred[1] + qred[2] + qred[3];
    const float mean = St * (1.0f / Hc);
    const float var  = Qt * (1.0f / Hc) - mean * mean;
    const float rs   = rsqrtf(var + 1e-5f);

    const int c = tid * 8;
    const float4 g0 = *(const float4*)(g + c), g1 = *(const float4*)(g + c + 4);
    const float4 b0 = *(const float4*)(b + c), b1 = *(const float4*)(b + c + 4);
    const float gg[8] = {g0.x, g0.y, g0.z, g0.w, g1.x, g1.y, g1.z, g1.w};
    const float bb[8] = {b0.x, b0.y, b0.z, b0.w, b1.x, b1.y, b1.z, b1.w};
    s16x8 m8;
    if (mul) m8 = *(const s16x8*)(mul + base);
    s16x8 o8;
#pragma unroll
    for (int j = 0; j < 8; j++) {
        float y = (x[j] - mean) * rs * gg[j] + bb[j];
        if (do_silu) y = y / (1.0f + __expf(-y));
        if (mul) y *= bf2f((u16)m8[j]);
        o8[j] = (short)f2bf(y);
    }
    *(s16x8*)(out + base) = o8;
}

// ---------- minGRU log-space CHUNKED parallel scan ----------
// Recurrence: lh_t = logaddexp(lh_{t-1} + c_t, v_t).  Chunk summary (C,V)
// composes as (C1+C2, logaddexp(V1+C2, V2)).  3 phases over CH=64 chunks of CL=32.
__device__ __forceinline__ void scan_step(float k, float p, float& ct, float& vt) {
    const float l1p = __logf(1.f + __expf(-fabsf(k)));
    ct = -(fmaxf(k, 0.f) + l1p);                      // -softplus(k)
    const float lg = (p >= 0.f) ? __logf(p + 0.5f)
                                : -(fmaxf(-p, 0.f) + __logf(1.f + __expf(-fabsf(p))));
    vt = -(fmaxf(-k, 0.f) + l1p) + lg;                // -softplus(-k) + log_g
}
__device__ __forceinline__ float laddexp(float a, float b) {
    const float m = fmaxf(a, b);
    return m + __logf(1.f + __expf(-fabsf(a - b)));
}

__global__ __launch_bounds__(256)
void scan_part1(const u16* __restrict__ kb, const u16* __restrict__ pb,
                float* __restrict__ Cc, float* __restrict__ Vv) {
    const int tid = threadIdx.x;
    const int hb = blockIdx.x & 7;          // H/256 = 8
    const int c  = (blockIdx.x >> 3) & 63;  // chunk
    const int b  = blockIdx.x >> 9;         // batch
    const int h  = hb * 256 + tid;
    size_t idx = (size_t)b * Sc * Hc + (size_t)(c * CL) * Hc + h;
    float C = 0.f, V = -1e30f;
#pragma unroll 4
    for (int t = 0; t < CL; t++) {
        float ct, vt;
        scan_step(bf2f(kb[idx]), bf2f(pb[idx]), ct, vt);
        V = laddexp(V + ct, vt);
        C += ct;
        idx += Hc;
    }
    const int chan = b * Hc + h;
    Cc[c * NCHAN + chan] = C;
    Vv[c * NCHAN + chan] = V;
}

__global__ __launch_bounds__(256)
void scan_mid(const float* __restrict__ Cc, const float* __restrict__ Vv,
              float* __restrict__ carry) {
    const int chan = blockIdx.x * 256 + threadIdx.x;  // 0..8191
    float lh = -0.69314718f;                          // log 0.5
    for (int c = 0; c < CH; c++) {
        carry[c * NCHAN + chan] = lh;
        lh = laddexp(lh + Cc[c * NCHAN + chan], Vv[c * NCHAN + chan]);
    }
}

__global__ __launch_bounds__(256)
void scan_part3(const u16* __restrict__ kb, const u16* __restrict__ pb,
                const float* __restrict__ carry, u16* __restrict__ out) {
    const int tid = threadIdx.x;
    const int hb = blockIdx.x & 7;
    const int c  = (blockIdx.x >> 3) & 63;
    const int b  = blockIdx.x >> 9;
    const int h  = hb * 256 + tid;
    size_t idx = (size_t)b * Sc * Hc + (size_t)(c * CL) * Hc + h;
    float lh = carry[c * NCHAN + (b * Hc + h)];
#pragma unroll 4
    for (int t = 0; t < CL; t++) {
        float ct, vt;
        scan_step(bf2f(kb[idx]), bf2f(pb[idx]), ct, vt);
        lh = laddexp(lh + ct, vt);
        out[idx] = f2bf(__expf(lh));
        idx += Hc;
    }
}

// ---------- casts ----------
__global__ __launch_bounds__(256)
void castf2b(const float* __restrict__ in, u16* __restrict__ out, int n) {
    const int i = (blockIdx.x * 256 + threadIdx.x) << 2;
    if (i >= n) return;
    const float4 v = *(const float4*)(in + i);
    u16x4 o;
    o.x = f2bf(v.x); o.y = f2bf(v.y); o.z = f2bf(v.z); o.w = f2bf(v.w);
    *(u16x4*)(out + i) = o;
}

// convW (H,H,3) -> wt (H, 3H): wt[o][k*H + i] = w[o][i][k]  (bf16)
__global__ __launch_bounds__(256)
void conv_tr(const float* __restrict__ w, u16* __restrict__ out) {
    const int idx = blockIdx.x * 256 + threadIdx.x;  // o*H + i
    const float* src = w + (size_t)idx * 3;
    const float a = src[0], b = src[1], c = src[2];
    const int o = idx >> 11, ii = idx & (Hc - 1);
    u16* dst = out + (size_t)o * (3 * Hc) + ii;
    dst[0]        = f2bf(a);
    dst[Hc]       = f2bf(b);
    dst[2 * Hc]   = f2bf(c);
}

// ---------- host ----------
static inline void launch_gemm(int conv, int epi,
                               const u16* A, const u16* Bw, const float* bias,
                               u16* Cb, float* Cf, const float* resid, u16* xout,
                               int M, int N, int K, int lda, const u16* zero, hipStream_t s) {
    dim3 grid(N / 128, M / 128), blk(256);
    if (conv)
        gemm_bt<1, 0><<<grid, blk, 0, s>>>(A, Bw, bias, Cb, Cf, resid, xout, M, N, K, lda, zero);
    else if (epi)
        gemm_bt<0, 1><<<grid, blk, 0, s>>>(A, Bw, bias, Cb, Cf, resid, xout, M, N, K, lda, zero);
    else
        gemm_bt<0, 0><<<grid, blk, 0, s>>>(A, Bw, bias, Cb, Cf, resid, xout, M, N, K, lda, zero);
}

extern "C" void kernel_launch(void* const* d_in, const int* in_sizes, int n_in,
                              void* d_out, int out_size, void* d_ws, size_t ws_size,
                              hipStream_t stream) {
    (void)in_sizes; (void)n_in; (void)out_size; (void)ws_size;
    const float* x0    = (const float*)d_in[0];
    const float* Wp1   = (const float*)d_in[1];
    const float* bp1   = (const float*)d_in[2];
    const float* Wp2   = (const float*)d_in[3];
    const float* bp2   = (const float*)d_in[4];
    const float* convW = (const float*)d_in[5];
    const float* convb = (const float*)d_in[6];
    const float* Wz    = (const float*)d_in[7];
    const float* bz    = (const float*)d_in[8];
    const float* Wh    = (const float*)d_in[9];
    const float* bh    = (const float*)d_in[10];
    const float* Wd    = (const float*)d_in[11];
    const float* bd    = (const float*)d_in[12];
    const float* lng   = (const float*)d_in[13];
    const float* lnb   = (const float*)d_in[14];
    float* out = (float*)d_out;

    // ws layout (bytes)
    char* ws = (char*)d_ws;
    u16* wbuf = (u16*)(ws);                       // 12,582,912 elems (max weight: conv)
    u16* s1   = (u16*)(ws + 25165824);            // 16,777,216 elems each below
    u16* t1   = (u16*)(ws + 58720256);
    u16* s2   = (u16*)(ws + 92274688);            // doubles as kb
    u16* pbuf = (u16*)(ws + 125829120);
    u16* xb   = (u16*)(ws + 159383552);           // 8,388,608 elems
    u16* zero = (u16*)(ws + 176160768);           // 1 KiB zero page
    float* scanC = (float*)(ws + 176161792);      // 64*8192 f32
    float* scanV = (float*)(ws + 178258944);
    float* carry = (float*)(ws + 180356096);

    hipMemsetAsync(zero, 0, 1024, stream);
    castf2b<<<dim3((Mc * Dc / 4) / 256), dim3(256), 0, stream>>>(x0, xb, Mc * Dc);

    const size_t wpStride = (size_t)Hc * Dc;      // 2,097,152
    const size_t cvStride = (size_t)Hc * Hc * 3;  // 12,582,912
    const size_t wzStride = (size_t)Hc * Hc;      // 4,194,304
    const size_t wdStride = (size_t)Dc * Hc;      // 2,097,152

    for (int i = 0; i < Lc; ++i) {
        const float* g0 = lng + ((size_t)i * 4 + 0) * Hc; const float* be0 = lnb + ((size_t)i * 4 + 0) * Hc;
        const float* g1 = lng + ((size_t)i * 4 + 1) * Hc; const float* be1 = lnb + ((size_t)i * 4 + 1) * Hc;
        const float* g2 = lng + ((size_t)i * 4 + 2) * Hc; const float* be2 = lnb + ((size_t)i * 4 + 2) * Hc;
        const float* g3 = lng + ((size_t)i * 4 + 3) * Hc; const float* be3 = lnb + ((size_t)i * 4 + 3) * Hc;

        // strand 1: proj1 + LN0
        castf2b<<<dim3((int)(wpStride / 4 / 256)), dim3(256), 0, stream>>>(Wp1 + i * wpStride, wbuf, (int)wpStride);
        launch_gemm(0, 0, xb, wbuf, bp1 + (size_t)i * Hc, t1, nullptr, nullptr, nullptr,
                    Mc, Hc, Dc, Dc, zero, stream);
        ln_fuse<<<dim3(Mc), dim3(256), 0, stream>>>(t1, s1, g0, be0, nullptr, 0);

        // conv1d (as GEMM over K=3H) + LN1 + SiLU
        conv_tr<<<dim3((Hc * Hc) / 256), dim3(256), 0, stream>>>(convW + i * cvStride, wbuf);
        launch_gemm(1, 0, s1, wbuf, convb + (size_t)i * Hc, t1, nullptr, nullptr, nullptr,
                    Mc, Hc, 3 * Hc, Hc, zero, stream);
        ln_fuse<<<dim3(Mc), dim3(256), 0, stream>>>(t1, s1, g1, be1, nullptr, 1);

        // minGRU: k = s1@Wz^T+bz ; p = s1@Wh^T+bh ; chunked scan ; LN2
        castf2b<<<dim3((int)(wzStride / 4 / 256)), dim3(256), 0, stream>>>(Wz + i * wzStride, wbuf, (int)wzStride);
        launch_gemm(0, 0, s1, wbuf, bz + (size_t)i * Hc, s2, nullptr, nullptr, nullptr,
                    Mc, Hc, Hc, Hc, zero, stream);
        castf2b<<<dim3((int)(wzStride / 4 / 256)), dim3(256), 0, stream>>>(Wh + i * wzStride, wbuf, (int)wzStride);
        launch_gemm(0, 0, s1, wbuf, bh + (size_t)i * Hc, pbuf, nullptr, nullptr, nullptr,
                    Mc, Hc, Hc, Hc, zero, stream);
        scan_part1<<<dim3(2048), dim3(256), 0, stream>>>(s2, pbuf, scanC, scanV);
        scan_mid<<<dim3(32), dim3(256), 0, stream>>>(scanC, scanV, carry);
        scan_part3<<<dim3(2048), dim3(256), 0, stream>>>(s2, pbuf, carry, t1);
        ln_fuse<<<dim3(Mc), dim3(256), 0, stream>>>(t1, s1, g2, be2, nullptr, 0);

        // strand 2: proj2 + LN3 + SiLU, fused multiply by s1 -> s2
        castf2b<<<dim3((int)(wpStride / 4 / 256)), dim3(256), 0, stream>>>(Wp2 + i * wpStride, wbuf, (int)wpStride);
        launch_gemm(0, 0, xb, wbuf, bp2 + (size_t)i * Hc, t1, nullptr, nullptr, nullptr,
                    Mc, Hc, Dc, Dc, zero, stream);
        ln_fuse<<<dim3(Mc), dim3(256), 0, stream>>>(t1, s2, g3, be3, s1, 1);

        // down proj + bias + residual; write fp32 x to d_out and bf16 x to xb
        castf2b<<<dim3((int)(wdStride / 4 / 256)), dim3(256), 0, stream>>>(Wd + i * wdStride, wbuf, (int)wdStride);
        launch_gemm(0, 1, s2, wbuf, bd + (size_t)i * Dc, nullptr, out,
                    (i == 0) ? x0 : out, xb, Mc, Dc, Hc, Hc, zero, stream);
    }
}